// Round 7
// baseline (1142.152 us; speedup 1.0000x reference)
//
#include <hip/hip_runtime.h>

// BasicBlock: N=32, C=256, H=W=56, two 3x3 convs (stride 1, pad 1), channel
// masks, training-mode BN, residual+ReLU. fp32 I/O; convs on bf16 MFMA.
#define N_   32
#define C_   256
#define H_   56
#define W_   56
#define HW_  (H_ * W_)        // 3136
#define NHW_ (N_ * HW_)       // 100352
#define LDS_STRIDE 15360      // u16 per LDS buffer (covers OOB-slack reads)

typedef unsigned short u16;
typedef __attribute__((ext_vector_type(8))) short short8;   // 8 bf16
typedef __attribute__((ext_vector_type(4))) float f32x4;

__device__ __forceinline__ float b2f(u16 u) {
    union { unsigned int i; float f; } v; v.i = ((unsigned int)u) << 16; return v.f;
}
__device__ __forceinline__ u16 f2b(float f) {
    union { float f; unsigned int i; } v; v.f = f;
    unsigned int r = v.i + 0x7fffu + ((v.i >> 16) & 1u);   // RNE
    return (u16)(r >> 16);
}

typedef const __attribute__((address_space(1))) unsigned int* as1_u32p;
typedef __attribute__((address_space(3))) unsigned int* as3_u32p;
__device__ __forceinline__ void gload_lds16(const u16* g, u16* l) {
    __builtin_amdgcn_global_load_lds((as1_u32p)g, (as3_u32p)l, 16, 0, 0);
}

// ---------------------------------------------------------------------------
// x (fp32 NCHW) -> xb (bf16 NHWC). Block = (n,h); LDS transpose, pad 57.
extern "C" __global__ __launch_bounds__(256) void cvt_x_kernel(
    const float* __restrict__ x, u16* __restrict__ xb)
{
    __shared__ float t[64 * 57];
    const int nh = blockIdx.x, n = nh / H_, h = nh % H_;
    for (int cb = 0; cb < 4; ++cb) {
        __syncthreads();
        for (int idx = threadIdx.x; idx < 64 * 56; idx += 256) {
            int cc = idx / 56, w = idx % 56;
            t[cc * 57 + w] = x[(((size_t)(n * C_ + cb * 64 + cc)) * H_ + h) * W_ + w];
        }
        __syncthreads();
        for (int idx = threadIdx.x; idx < 56 * 64; idx += 256) {
            int w = idx >> 6, cc = idx & 63;
            xb[(((size_t)(n * H_ + h) * W_) + w) * C_ + cb * 64 + cc] = f2b(t[cc * 57 + w]);
        }
    }
}

// ---------------------------------------------------------------------------
// W [co][ci][3][3] fp32 -> wpA [rs][cih 8][cog 16][l15 16][lq 4][j 8] bf16.
extern "C" __global__ __launch_bounds__(256) void pack_w_kernel(
    const float* __restrict__ w, u16* __restrict__ wp)
{
    int o = blockIdx.x * 256 + threadIdx.x;      // grid 2304 -> 589824
    int j = o & 7, lq = (o >> 3) & 3, l15 = (o >> 5) & 15;
    int cog = (o >> 9) & 15, cih = (o >> 13) & 7, rs = o >> 16;
    int co = cog * 16 + l15;
    int ci = cih * 32 + lq * 8 + j;
    wp[o] = f2b(w[((size_t)co * C_ + ci) * 9 + rs]);
}

// ---------------------------------------------------------------------------
// Implicit-GEMM 3x3 conv, MERGED co (all 256 per block) + double-buffered
// async staging + fused BN-stats epilogue.
// Grid 896 = n*28 + hb (2 output rows). 4 waves: wave>>1 = co half (128 co),
// wave&1 = output row. Wave tile 128co x 64px = 8x4 grid of 16x16x32 MFMA.
// LDS: 2 buffers x [4 halo rows][58 slots][64 ci] bf16, 16B octs XOR-swizzled
// by slot, staged via global_load_lds (swizzle baked into global address).
// stage(cc+1) issues right after the barrier -> in flight during compute(cc).
extern "C" __global__ __launch_bounds__(256, 2) void BasicBlock_4355096838467_kernel(
    const u16* __restrict__ xb,     // [N][56][56][256] bf16
    const u16* __restrict__ wpA,    // packed weights
    const float* __restrict__ mask,
    const u16* __restrict__ zeropad,
    u16* __restrict__ outb,         // [N][56][56][256] bf16
    float* __restrict__ gsum,       // [256] BN sum accumulator (pre-zeroed)
    float* __restrict__ gsq)        // [256] BN sumsq accumulator
{
    __shared__ u16 lds[2][LDS_STRIDE];   // 61440 B total; 14848 u16 used/buf

    const int tid  = threadIdx.x;
    const int wave = tid >> 6, lane = tid & 63;
    const int l15  = lane & 15, lq = lane >> 4;
    const int wave_co = wave >> 1, wave_px = wave & 1;
    const int n = blockIdx.x / 28, hb = blockIdx.x % 28;
    const int h0 = hb * 2;
    const size_t abase0 = (size_t)wave_co * 4096 + (size_t)(l15 * 32 + lq * 8);

    f32x4 acc[8][4];
#pragma unroll
    for (int i = 0; i < 8; ++i)
#pragma unroll
        for (int j = 0; j < 4; ++j) acc[i][j] = (f32x4){0.f, 0.f, 0.f, 0.f};

    // stage 64-ci chunk cc into LDS buffer b (29 x 1KB async loads/block)
    auto stage = [&](int cc, int b) {
        const int c0 = cc * 64;
        for (int is = wave; is < 29; is += 4) {
            int L = is * 64 + lane;           // 0..1855
            int pixel = L >> 3, so = L & 7;
            int rr = pixel / 58, slot = pixel - rr * 58;
            int oct = so ^ (slot & 7);
            int row = h0 - 1 + rr, col = slot - 1;
            const u16* gp = ((unsigned)row < (unsigned)H_ && (unsigned)col < (unsigned)W_)
                ? xb + (((size_t)(n * H_ + row) * W_ + col) << 8) + c0 + oct * 8
                : zeropad + oct * 8;
            gload_lds16(gp, &lds[b][is * 512]);
        }
    };

    stage(0, 0);
    for (int cc = 0; cc < 4; ++cc) {
        __syncthreads();                      // drains stage(cc)
        if (cc < 3) stage(cc + 1, (cc + 1) & 1);   // async, hidden by compute
        const u16* lb = lds[cc & 1];

        short8 afq[2][8];
        auto loadA = [&](int t, short8* dst) {
            const int rs = t >> 1, kk = t & 1;
            const size_t ba = (size_t)rs * 65536 + (size_t)(cc * 2 + kk) * 8192 + abase0;
#pragma unroll
            for (int fm = 0; fm < 8; ++fm)
                dst[fm] = *(const short8*)(wpA + ba + (size_t)fm * 512);
        };
        loadA(0, afq[0]);
#pragma unroll
        for (int t = 0; t < 18; ++t) {
            if (t < 17) loadA(t + 1, afq[(t + 1) & 1]);
            const int rs = t >> 1, kk = t & 1;
            const int r = rs / 3, s = rs - r * 3;
            short8 bfr[4];
#pragma unroll
            for (int fn = 0; fn < 4; ++fn) {
                int slot = fn * 16 + l15 + s;
                int pixel = (wave_px + r) * 58 + slot;
                int so = (kk * 4 + lq) ^ (slot & 7);
                bfr[fn] = *(const short8*)(lb + pixel * 64 + so * 8);
            }
#pragma unroll
            for (int fm = 0; fm < 8; ++fm)
#pragma unroll
                for (int fn = 0; fn < 4; ++fn)
                    acc[fm][fn] = __builtin_amdgcn_mfma_f32_16x16x32_bf16(
                        afq[t & 1][fm], bfr[fn], acc[fm][fn], 0, 0, 0);
        }
    }

    // Epilogue: C/D col=lane&15 (pixel), row=lq*4+reg (co). Mask folded;
    // BN sum/sumsq computed in-register (shfl over l15) + atomicAdd.
    const int row = h0 + wave_px;
#pragma unroll
    for (int fm = 0; fm < 8; ++fm) {
        const int co_b = wave_co * 128 + fm * 16 + lq * 4;
        const f32x4 mk = *(const f32x4*)(mask + co_b);
        f32x4 s = (f32x4){0.f, 0.f, 0.f, 0.f};
        f32x4 q = (f32x4){0.f, 0.f, 0.f, 0.f};
#pragma unroll
        for (int fn = 0; fn < 4; ++fn) {
            int px = fn * 16 + l15;
            f32x4 v;
#pragma unroll
            for (int r = 0; r < 4; ++r) v[r] = acc[fm][fn][r] * mk[r];
            if (px < W_) {
                size_t base = (((size_t)(n * H_ + row) * W_ + px) << 8) + co_b;
                ushort4 o;
                o.x = f2b(v[0]); o.y = f2b(v[1]); o.z = f2b(v[2]); o.w = f2b(v[3]);
                *(ushort4*)(outb + base) = o;
#pragma unroll
                for (int r = 0; r < 4; ++r) { s[r] += v[r]; q[r] += v[r] * v[r]; }
            }
        }
#pragma unroll
        for (int m = 1; m <= 8; m <<= 1) {
#pragma unroll
            for (int r = 0; r < 4; ++r) {
                s[r] += __shfl_xor(s[r], m);
                q[r] += __shfl_xor(q[r], m);
            }
        }
        if (l15 == 0) {
#pragma unroll
            for (int r = 0; r < 4; ++r) {
                atomicAdd(&gsum[co_b + r], s[r]);
                atomicAdd(&gsq[co_b + r], q[r]);
            }
        }
    }
}

// ---------------------------------------------------------------------------
// zero stats accumulators + scale/shift + zeropad scratch (12 KB). grid 12.
extern "C" __global__ void zero_accum_kernel(float* __restrict__ p) {
    p[blockIdx.x * 256 + threadIdx.x] = 0.f;
}

// scale/shift from accumulated stats. 1 block x 256.
extern "C" __global__ void finalize_bn_kernel(
    const float* __restrict__ gsum, const float* __restrict__ gsq,
    const float* __restrict__ gamma, const float* __restrict__ beta,
    float* __restrict__ scale, float* __restrict__ shift)
{
    const int c = threadIdx.x;
    const float inv_n = 1.f / (float)NHW_;
    float mean = gsum[c] * inv_n;
    float var  = gsq[c] * inv_n - mean * mean;
    var = fmaxf(var, 0.f);
    float inv = rsqrtf(var + 1e-5f);
    float sc = gamma[c] * inv;
    scale[c] = sc;
    shift[c] = beta[c] - mean * sc;
}

// In-place BN+ReLU on NHWC bf16. grid 12544, 8 elems/thread.
extern "C" __global__ __launch_bounds__(256) void bn_relu_nhwc_kernel(
    u16* __restrict__ hb, const float* __restrict__ scale, const float* __restrict__ shift)
{
    size_t idx = ((size_t)blockIdx.x * 256 + threadIdx.x) * 8;
    int c0 = (int)(idx & 255);
    short8 v = *(short8*)(hb + idx);
    short8 o;
#pragma unroll
    for (int j = 0; j < 8; ++j) {
        int c = c0 + j;
        float f = b2f((u16)v[j]) * scale[c] + shift[c];
        o[j] = (short)f2b(fmaxf(f, 0.f));
    }
    *(short8*)(hb + idx) = o;
}

// out = relu(bn2(h2) + x): NHWC bf16 -> NCHW fp32 via LDS transpose. grid (n,h).
extern "C" __global__ __launch_bounds__(256) void bn_add_relu_out_kernel(
    const u16* __restrict__ h2b, const float* __restrict__ x,
    const float* __restrict__ scale, const float* __restrict__ shift,
    float* __restrict__ out)
{
    __shared__ float t[64 * 57];
    const int nh = blockIdx.x, n = nh / H_, h = nh % H_;
    const size_t pixbase = ((size_t)(n * H_ + h) * W_) << 8;
    for (int cb = 0; cb < 4; ++cb) {
        __syncthreads();
        for (int it = threadIdx.x; it < 448; it += 256) {      // 56 px * 8 octs
            int w = it >> 3, oc = it & 7;
            short8 v = *(const short8*)(h2b + pixbase + ((size_t)w << 8) + cb * 64 + oc * 8);
#pragma unroll
            for (int j = 0; j < 8; ++j) t[(oc * 8 + j) * 57 + w] = b2f((u16)v[j]);
        }
        __syncthreads();
        for (int it = threadIdx.x; it < 64 * 56; it += 256) {
            int cl = it / 56, w = it % 56;
            int c = cb * 64 + cl;
            size_t oidx = ((size_t)(n * C_ + c) * H_ + h) * W_ + w;
            float v = t[cl * 57 + w] * scale[c] + shift[c] + x[oidx];
            out[oidx] = fmaxf(v, 0.f);
        }
    }
}

// ---------------------------------------------------------------------------
extern "C" void kernel_launch(void* const* d_in, const int* in_sizes, int n_in,
                              void* d_out, int out_size, void* d_ws, size_t ws_size,
                              hipStream_t stream) {
    const float* x      = (const float*)d_in[0];
    const float* W1     = (const float*)d_in[1];
    const float* W2     = (const float*)d_in[2];
    const float* gamma1 = (const float*)d_in[3];
    const float* beta1  = (const float*)d_in[4];
    const float* gamma2 = (const float*)d_in[5];
    const float* beta2  = (const float*)d_in[6];
    const float* mask1  = (const float*)d_in[7];
    const float* mask2  = (const float*)d_in[8];
    float* out = (float*)d_out;

    // ws layout (no overlaps):
    // [0,4K)   stats accumulators (gsum1,gsq1,gsum2,gsq2)
    // [4K,8K)  scale1,shift1,scale2,shift2
    // [8K,12K) zeropad scratch (zeroed every launch, read-only thereafter)
    // [12K,..) Wp1 | Wp2 | xb (reused as h2b)
    char* ws = (char*)d_ws;
    float* gsum1  = (float*)ws;
    float* gsq1   = gsum1 + 256;
    float* gsum2  = gsq1 + 256;
    float* gsq2   = gsum2 + 256;
    float* scale1 = gsq2 + 256;
    float* shift1 = scale1 + 256;
    float* scale2 = shift1 + 256;
    float* shift2 = scale2 + 256;
    u16* zeropad = (u16*)(ws + 8192);
    u16* Wp1 = (u16*)(ws + 12288);
    u16* Wp2 = Wp1 + 9 * 256 * 256;
    u16* xb  = Wp2 + 9 * 256 * 256;
    u16* h2b = xb;                          // xb dead after conv1
    u16* h1b = (u16*)d_out;                 // bf16 scratch inside fp32 output

    zero_accum_kernel<<<dim3(12), dim3(256), 0, stream>>>(gsum1);
    cvt_x_kernel<<<dim3(N_ * H_), dim3(256), 0, stream>>>(x, xb);
    pack_w_kernel<<<dim3(2304), dim3(256), 0, stream>>>(W1, Wp1);
    pack_w_kernel<<<dim3(2304), dim3(256), 0, stream>>>(W2, Wp2);

    BasicBlock_4355096838467_kernel<<<dim3(N_ * 28), dim3(256), 0, stream>>>(
        xb, Wp1, mask1, zeropad, h1b, gsum1, gsq1);
    finalize_bn_kernel<<<dim3(1), dim3(256), 0, stream>>>(gsum1, gsq1, gamma1, beta1, scale1, shift1);
    bn_relu_nhwc_kernel<<<dim3(12544), dim3(256), 0, stream>>>(h1b, scale1, shift1);

    BasicBlock_4355096838467_kernel<<<dim3(N_ * 28), dim3(256), 0, stream>>>(
        h1b, Wp2, mask2, zeropad, h2b, gsum2, gsq2);
    finalize_bn_kernel<<<dim3(1), dim3(256), 0, stream>>>(gsum2, gsq2, gamma2, beta2, scale2, shift2);
    bn_add_relu_out_kernel<<<dim3(N_ * H_), dim3(256), 0, stream>>>(h2b, x, scale2, shift2, out);
}